// Round 3
// baseline (996.223 us; speedup 1.0000x reference)
//
#include <hip/hip_runtime.h>
#include <math.h>

// Problem constants (match reference)
#define Bc 4
#define Cc 16
#define Hc 128
#define Gc 64

// Tile: 4x4x32 voxels per 256-thread block; each thread owns voxels (tx, tx+16)
#define TZ 4
#define TY 4
#define TXH 16                      // thread x-extent
#define TXX 32                      // tile x-extent (2 voxels/thread)
#define HZ (TZ + 2)
#define HY (TY + 2)
#define HXX (TXX + 2)               // 34
#define HALO_PER_C (HZ * HY * HXX)  // 1224 floats per channel
#define CH_PER_PASS 4
#define NPASS (Cc / CH_PER_PASS)    // 4

__global__ __launch_bounds__(256, 2) void nca_fused(
    const float* __restrict__ x,
    const float* __restrict__ W1,
    const float* __restrict__ b1,
    const float* __restrict__ W2,
    const float* __restrict__ stoch,
    float* __restrict__ out)
{
    // LDS: 32768 + 8192 + 512 + 19584 = 61056 B  -> 2 blocks/CU
    __shared__ float w1s[Hc * 64];
    __shared__ float w2ts[Hc * Cc];   // transposed: [h][k]
    __shared__ float b1s[Hc];
    __shared__ float xs[CH_PER_PASS * HALO_PER_C];

    const int tid = threadIdx.x;

    int bid = blockIdx.x;
    const int xt = bid & 1; bid >>= 1;            // Gc/TXX = 2
    const int yt = bid & 15; bid >>= 4;           // Gc/TY = 16
    const int zt = bid & 15; bid >>= 4;           // Gc/TZ = 16
    const int b  = bid;

    const int z0 = zt * TZ, y0 = yt * TY, x0 = xt * TXX;

    // ---- Stage weights into LDS (once per block) ----
    {
        const float4* W1v = (const float4*)W1;
        float4* w1sv = (float4*)w1s;
#pragma unroll
        for (int i = 0; i < (Hc * 64 / 4) / 256; ++i)   // 8
            w1sv[tid + i * 256] = W1v[tid + i * 256];
        if (tid < Hc) b1s[tid] = b1[tid];
#pragma unroll
        for (int i = 0; i < (Cc * Hc) / 256; ++i) {     // 8
            const int idx = tid + i * 256;
            const int k = idx >> 7;        // idx / Hc
            const int h = idx & (Hc - 1);  // idx % Hc
            w2ts[h * Cc + k] = W2[idx];
        }
    }

    const int tx = tid & 15;
    const int ty = (tid >> 4) & 3;
    const int tz = tid >> 6;

    // ---- Perception in four 4-channel passes; 2 voxels per thread ----
    float p0[64], p1[64];
    float pool0 = -1e30f, pool1 = -1e30f;

#pragma unroll
    for (int pass = 0; pass < NPASS; ++pass) {
        __syncthreads();  // weights staged (pass 0) / xs no longer read
        for (int idx = tid; idx < CH_PER_PASS * HALO_PER_C; idx += 256) {
            int hx = idx % HXX;
            int t  = idx / HXX;
            int hy = t % HY; t /= HY;
            int hz = t % HZ;
            int cc = t / HZ;
            const int c = pass * CH_PER_PASS + cc;
            int gz = z0 + hz - 1, gy = y0 + hy - 1, gx = x0 + hx - 1;
            float v = 0.0f;
            if ((unsigned)gz < (unsigned)Gc && (unsigned)gy < (unsigned)Gc &&
                (unsigned)gx < (unsigned)Gc) {
                v = x[(((b * Cc + c) * Gc + gz) * Gc + gy) * Gc + gx];
            }
            xs[idx] = v;
        }
        __syncthreads();

#pragma unroll
        for (int cc = 0; cc < CH_PER_PASS; ++cc) {
            const int g = pass * CH_PER_PASS + cc;  // global channel
            const float* xc = &xs[cc * HALO_PER_C];
            float S0[3][3], D0[3][3], S1[3][3], D1[3][3];
            float c0 = 0.0f, c1 = 0.0f;
#pragma unroll
            for (int dz = 0; dz < 3; ++dz) {
#pragma unroll
                for (int dy = 0; dy < 3; ++dy) {
                    const int base = (tz + dz) * (HY * HXX) + (ty + dy) * HXX + tx;
                    const float a0 = xc[base + 0];
                    const float m0 = xc[base + 1];
                    const float q0 = xc[base + 2];
                    const float a1 = xc[base + 16];
                    const float m1 = xc[base + 17];
                    const float q1 = xc[base + 18];
                    S0[dz][dy] = a0 + 2.0f * m0 + q0;
                    D0[dz][dy] = q0 - a0;
                    S1[dz][dy] = a1 + 2.0f * m1 + q1;
                    D1[dz][dy] = q1 - a1;
                    if (dz == 1 && dy == 1) { c0 = m0; c1 = m1; }
                    if (g == 3) {
                        pool0 = fmaxf(pool0, fmaxf(fmaxf(a0, m0), q0));
                        pool1 = fmaxf(pool1, fmaxf(fmaxf(a1, m1), q1));
                    }
                }
            }
            const float sx0 = (D0[0][0] + 2.0f * D0[0][1] + D0[0][2])
                      + 2.0f * (D0[1][0] + 2.0f * D0[1][1] + D0[1][2])
                      +        (D0[2][0] + 2.0f * D0[2][1] + D0[2][2]);
            const float sy0 = (S0[0][2] - S0[0][0])
                      + 2.0f * (S0[1][2] - S0[1][0])
                      +        (S0[2][2] - S0[2][0]);
            const float sz0 = (S0[2][0] + 2.0f * S0[2][1] + S0[2][2])
                            - (S0[0][0] + 2.0f * S0[0][1] + S0[0][2]);
            const float sx1 = (D1[0][0] + 2.0f * D1[0][1] + D1[0][2])
                      + 2.0f * (D1[1][0] + 2.0f * D1[1][1] + D1[1][2])
                      +        (D1[2][0] + 2.0f * D1[2][1] + D1[2][2]);
            const float sy1 = (S1[0][2] - S1[0][0])
                      + 2.0f * (S1[1][2] - S1[1][0])
                      +        (S1[2][2] - S1[2][0]);
            const float sz1 = (S1[2][0] + 2.0f * S1[2][1] + S1[2][2])
                            - (S1[0][0] + 2.0f * S1[0][1] + S1[0][2]);
            p0[4 * g + 0] = c0; p0[4 * g + 1] = sx0;
            p0[4 * g + 2] = sy0; p0[4 * g + 3] = sz0;
            p1[4 * g + 0] = c1; p1[4 * g + 1] = sx1;
            p1[4 * g + 2] = sy1; p1[4 * g + 3] = sz1;
        }
    }

    // Zero-pad equivalent to -inf pad for alive test since thresh 0.1 > 0
    const float alive0 = (pool0 > 0.1f) ? 1.0f : 0.0f;
    const float alive1 = (pool1 > 0.1f) ? 1.0f : 0.0f;

    // ---- MLP for both voxels: each weight ds_read_b128 feeds 8 FMAs ----
    float dx0[16], dx1[16];
#pragma unroll
    for (int k = 0; k < 16; ++k) { dx0[k] = 0.0f; dx1[k] = 0.0f; }

    const float4* w1sv  = (const float4*)w1s;
    const float4* w2tsv = (const float4*)w2ts;
    const float4* b1sv  = (const float4*)b1s;

#pragma unroll 1
    for (int o = 0; o < Hc; o += 8) {
        float acc0[8], acc1[8];
        {
            const float4 ba = b1sv[(o >> 2) + 0];
            const float4 bb = b1sv[(o >> 2) + 1];
            acc0[0] = ba.x; acc0[1] = ba.y; acc0[2] = ba.z; acc0[3] = ba.w;
            acc0[4] = bb.x; acc0[5] = bb.y; acc0[6] = bb.z; acc0[7] = bb.w;
#pragma unroll
            for (int i = 0; i < 8; ++i) acc1[i] = acc0[i];
        }
        const float4* wb = w1sv + o * 16;  // row o, float4 units
#pragma unroll
        for (int c4 = 0; c4 < 16; ++c4) {
#pragma unroll
            for (int i = 0; i < 8; ++i) {
                const float4 w = wb[i * 16 + c4];
                acc0[i] = fmaf(w.x, p0[4 * c4 + 0], acc0[i]);
                acc0[i] = fmaf(w.y, p0[4 * c4 + 1], acc0[i]);
                acc0[i] = fmaf(w.z, p0[4 * c4 + 2], acc0[i]);
                acc0[i] = fmaf(w.w, p0[4 * c4 + 3], acc0[i]);
                acc1[i] = fmaf(w.x, p1[4 * c4 + 0], acc1[i]);
                acc1[i] = fmaf(w.y, p1[4 * c4 + 1], acc1[i]);
                acc1[i] = fmaf(w.z, p1[4 * c4 + 2], acc1[i]);
                acc1[i] = fmaf(w.w, p1[4 * c4 + 3], acc1[i]);
            }
        }
        const float4* w2b = w2tsv + o * 4;  // row h=o, float4 units
#pragma unroll
        for (int i = 0; i < 8; ++i) {
            const float h0 = fmaxf(acc0[i], 0.0f);
            const float h1 = fmaxf(acc1[i], 0.0f);
#pragma unroll
            for (int k4 = 0; k4 < 4; ++k4) {
                const float4 w = w2b[i * 4 + k4];
                dx0[4 * k4 + 0] = fmaf(w.x, h0, dx0[4 * k4 + 0]);
                dx0[4 * k4 + 1] = fmaf(w.y, h0, dx0[4 * k4 + 1]);
                dx0[4 * k4 + 2] = fmaf(w.z, h0, dx0[4 * k4 + 2]);
                dx0[4 * k4 + 3] = fmaf(w.w, h0, dx0[4 * k4 + 3]);
                dx1[4 * k4 + 0] = fmaf(w.x, h1, dx1[4 * k4 + 0]);
                dx1[4 * k4 + 1] = fmaf(w.y, h1, dx1[4 * k4 + 1]);
                dx1[4 * k4 + 2] = fmaf(w.z, h1, dx1[4 * k4 + 2]);
                dx1[4 * k4 + 3] = fmaf(w.w, h1, dx1[4 * k4 + 3]);
            }
        }
    }

    // ---- Epilogue: stochastic update, alive mask, angle wrap (2 voxels) ----
    const int gz = z0 + tz, gy = y0 + ty;
    const int gx0 = x0 + tx, gx1 = x0 + tx + 16;
    const int vox0 = ((b * Gc + gz) * Gc + gy) * Gc + gx0;
    const int vox1 = vox0 + 16;
    const float sm0 = (stoch[vox0] <= 0.5f) ? 1.0f : 0.0f;
    const float sm1 = (stoch[vox1] <= 0.5f) ? 1.0f : 0.0f;

    const float TWO_PI_F = 6.2831854820251464844f;

    const int obase = (((b * Cc) * Gc + gz) * Gc + gy) * Gc;
#pragma unroll
    for (int k = 0; k < 16; ++k) {
        const float xn0 = p0[4 * k] + dx0[k] * sm0;
        const float xn1 = p1[4 * k] + dx1[k] * sm1;
        float r0, r1;
        if (k < 15) {
            r0 = xn0 * alive0;
            r1 = xn1 * alive1;
        } else {
            r0 = fmodf(xn0, TWO_PI_F); if (r0 < 0.0f) r0 += TWO_PI_F;
            r1 = fmodf(xn1, TWO_PI_F); if (r1 < 0.0f) r1 += TWO_PI_F;
        }
        out[obase + k * (Gc * Gc * Gc) + gx0] = r0;
        out[obase + k * (Gc * Gc * Gc) + gx1] = r1;
    }
}

extern "C" void kernel_launch(void* const* d_in, const int* in_sizes, int n_in,
                              void* d_out, int out_size, void* d_ws, size_t ws_size,
                              hipStream_t stream) {
    const float* x     = (const float*)d_in[0];
    // d_in[1] = percep_kernel: fixed sobel structure, hardcoded in kernel
    const float* W1    = (const float*)d_in[2];
    const float* b1    = (const float*)d_in[3];
    const float* W2    = (const float*)d_in[4];
    const float* stoch = (const float*)d_in[5];
    float* out = (float*)d_out;

    const int nblocks = Bc * (Gc / TZ) * (Gc / TY) * (Gc / TXX);  // 2048
    nca_fused<<<nblocks, 256, 0, stream>>>(x, W1, b1, W2, stoch, out);
}